// Round 3
// baseline (281.568 us; speedup 1.0000x reference)
//
#include <hip/hip_runtime.h>
#include <hip/hip_bf16.h>

// Problem constants (fixed by the reference)
#define B_DIM   16384
#define IN_DIM  512
#define H_DIM   512
#define K_DIM   1024          // IN + H concatenated
#define N4H     2048          // 4*H
#define BH      (B_DIM * H_DIM)

typedef __attribute__((ext_vector_type(8)))  short  short8;   // 8 bf16 = one MFMA operand
typedef __attribute__((ext_vector_type(4)))  short  short4v;  // 4 bf16 = 8B write
typedef __attribute__((ext_vector_type(4)))  float  f32x4;
typedef __attribute__((ext_vector_type(16))) float  f32x16;   // 32x32 accumulator

__device__ inline void async_load16(const void* g, void* l) {
    __builtin_amdgcn_global_load_lds(
        (const __attribute__((address_space(1))) void*)g,
        (__attribute__((address_space(3)))       void*)l, 16, 0, 0);
}

__device__ inline short bf16bits(float f) {
    __hip_bfloat16 b = __float2bfloat16(f);
    return *reinterpret_cast<short*>(&b);
}

__device__ inline float sigmoidf_(float v) {
    return 1.0f / (1.0f + __expf(-v));
}
__device__ inline float tanhf_(float v) {
    v = fminf(fmaxf(v, -30.f), 30.f);
    float e = __expf(2.f * v);
    return (e - 1.f) / (e + 1.f);
}

// ---------------------------------------------------------------------------
// Combined prep (validated in R2):
//   blocks [0,2048):   Wt[row][k] bf16, row permuted nb*128 + gate*32 + col
//   blocks [2048,4096): Axh[m][k] bf16 = x[m]||h[m]
// ---------------------------------------------------------------------------
__global__ __launch_bounds__(256) void prep_all(
    const float* __restrict__ Wx, const float* __restrict__ Wh,
    const float* __restrict__ bx, const float* __restrict__ bh,
    const float* __restrict__ x,  const float* __restrict__ h,
    __hip_bfloat16* __restrict__ Wt, __hip_bfloat16* __restrict__ Axh,
    float* __restrict__ bias_p) {
    const int bid = blockIdx.x;
    const int t   = threadIdx.x;

    if (bid < 2048) {
        __shared__ __hip_bfloat16 tile[32][33];
        const int bk = bid & 31;
        const int bn = bid >> 5;
        const int kb = bk * 32, nb = bn * 32;
#pragma unroll
        for (int r = 0; r < 4; ++r) {
            int k_loc = r * 8 + (t >> 5);
            int n_loc = t & 31;
            int kg = kb + k_loc;
            float v = (kg < IN_DIM) ? Wx[(size_t)kg * N4H + nb + n_loc]
                                    : Wh[(size_t)(kg - IN_DIM) * N4H + nb + n_loc];
            tile[k_loc][n_loc] = __float2bfloat16(v);
        }
        __syncthreads();
        {
            int n_loc = t >> 3;
            int k_loc = (t & 7) * 4;
            int ng = nb + n_loc;
            int g  = ng >> 9;
            int c  = ng & 511;
            int row_out = (c >> 5) * 128 + g * 32 + (c & 31);
            short4v v4;
            v4.x = *reinterpret_cast<short*>(&tile[k_loc + 0][n_loc]);
            v4.y = *reinterpret_cast<short*>(&tile[k_loc + 1][n_loc]);
            v4.z = *reinterpret_cast<short*>(&tile[k_loc + 2][n_loc]);
            v4.w = *reinterpret_cast<short*>(&tile[k_loc + 3][n_loc]);
            *(short4v*)&Wt[(size_t)row_out * K_DIM + kb + k_loc] = v4;
        }
        if (bid < 8) {
            int ng = bid * 256 + t;
            int g  = ng >> 9;
            int c  = ng & 511;
            int ro = (c >> 5) * 128 + g * 32 + (c & 31);
            bias_p[ro] = bx[ng] + bh[ng];
        }
    } else {
        const int ab = bid - 2048;              // 0..2047, 8 rows each
        const int kq = t;                       // float4 index within row
        const float* src = (kq < 128) ? (x + kq * 4)
                                      : (h + (size_t)(kq - 128) * 4);
#pragma unroll
        for (int j = 0; j < 8; ++j) {
            int m = ab * 8 + j;
            float4 v = *(const float4*)(src + (size_t)m * 512);
            short4v sv;
            sv.x = bf16bits(v.x);
            sv.y = bf16bits(v.y);
            sv.z = bf16bits(v.z);
            sv.w = bf16bits(v.w);
            *(short4v*)&Axh[(size_t)m * K_DIM + kq * 4] = sv;
        }
    }
}

// ---------------------------------------------------------------------------
// Main fused kernel. 128x128 tile, BK=64 (16 K-iters), mfma_f32_32x32x16_bf16.
// LDS rows are 64 bf16 = 128 B = 8 16B-slots; row stride == 32 banks, so slot
// s of row r holds k-group q = s ^ (r&7) (XOR swizzle). Tile bases are 0 mod
// 32 rows -> swizzle term == (lane&7) everywhere.
// Staging via global_load_lds w=16 with the XOR applied to the GLOBAL fetch
// address (LDS side must stay lane-contiguous, m104).
// XCD swizzle: 16 bn-blocks sharing a bm pinned to one XCD (A-tile L2 reuse).
// ---------------------------------------------------------------------------
__global__ __launch_bounds__(256, 4) void lstm_gemm(
    const float* __restrict__ c_in,
    const __hip_bfloat16* __restrict__ Axh,
    const __hip_bfloat16* __restrict__ Wt,
    const float* __restrict__ bias_p,
    float* __restrict__ out) {
    __shared__ __hip_bfloat16 lds_a[128 * 64];   // 16KB
    __shared__ __hip_bfloat16 lds_b[128 * 64];   // 16KB

    const int tid  = threadIdx.x;
    const int w    = tid >> 6;
    const int lane = tid & 63;
    const int l31  = lane & 31;
    const int half = lane >> 5;

    // XCD-aware decomposition (round-robin block->XCD assumed: j & 7)
    const int jb    = blockIdx.x;
    const int xcd   = jb & 7;
    const int local = jb >> 3;                   // 0..255 per XCD
    const int bm    = xcd * 16 + (local >> 4);   // 0..127
    const int bn    = local & 15;                // 0..15

    f32x16 acc[4];
#pragma unroll
    for (int ni = 0; ni < 4; ++ni)
#pragma unroll
        for (int r = 0; r < 16; ++r)
            acc[ni][r] = 0.f;

    const __hip_bfloat16* Ab = Axh + (size_t)bm * 128 * K_DIM;
    const __hip_bfloat16* Bb = Wt  + (size_t)bn * 128 * K_DIM;

    // ---- staging geometry (wave w fills LDS slots [w*256, w*256+256)) ----
    // instruction j covers slots S = w*256 + j*64 + lane; r = S>>3, s = S&7,
    // global k-group q = s ^ (r&7) = (lane&7) ^ ((lane>>3)&7).
    const int r_base = w * 32 + (lane >> 3);
    const int q8     = (((lane & 7) ^ ((lane >> 3) & 7)) * 8);
    size_t g_off[4];
    __hip_bfloat16* lA[4];
    __hip_bfloat16* lB[4];
#pragma unroll
    for (int j = 0; j < 4; ++j) {
        g_off[j] = (size_t)(r_base + j * 8) * K_DIM + q8;
        lA[j] = lds_a + w * 2048 + j * 512;
        lB[j] = lds_b + w * 2048 + j * 512;
    }

    // ---- ds_read offsets: row = base + l31, byte = row*128 + slot*16,
    //      slot = (sk*2 + half) ^ (lane&7). 4 VGPRs cover all A and B reads.
    int rd_off[4];
#pragma unroll
    for (int sk = 0; sk < 4; ++sk)
        rd_off[sk] = l31 * 128 + (((sk * 2 + half) ^ (lane & 7)) * 16);

    // ---- prefetch c (epilogue operand) into registers; latency hidden ----
    const int col = bn * 32 + l31;               // global h-column
    float c_reg[16];
#pragma unroll
    for (int reg = 0; reg < 16; ++reg) {
        int m_loc = (reg & 3) + 8 * (reg >> 2) + 4 * half;
        c_reg[reg] = c_in[(size_t)(bm * 128 + w * 32 + m_loc) * H_DIM + col];
    }

    const char* lap = (const char*)lds_a + w * 4096;
    const char* lbp = (const char*)lds_b;

    for (int kt = 0; kt < 16; ++kt) {
        const int kb = kt * 64;
#pragma unroll
        for (int j = 0; j < 4; ++j) {
            async_load16(Ab + g_off[j] + kb, lA[j]);
            async_load16(Bb + g_off[j] + kb, lB[j]);
        }
        __syncthreads();

#pragma unroll
        for (int sk = 0; sk < 4; ++sk) {
            short8 af = *(const short8*)(lap + rd_off[sk]);
            short8 bf0 = *(const short8*)(lbp + 0 * 4096 + rd_off[sk]);
            short8 bf1 = *(const short8*)(lbp + 1 * 4096 + rd_off[sk]);
            short8 bf2 = *(const short8*)(lbp + 2 * 4096 + rd_off[sk]);
            short8 bf3 = *(const short8*)(lbp + 3 * 4096 + rd_off[sk]);
            acc[0] = __builtin_amdgcn_mfma_f32_32x32x16_bf16(af, bf0, acc[0], 0, 0, 0);
            acc[1] = __builtin_amdgcn_mfma_f32_32x32x16_bf16(af, bf1, acc[1], 0, 0, 0);
            acc[2] = __builtin_amdgcn_mfma_f32_32x32x16_bf16(af, bf2, acc[2], 0, 0, 0);
            acc[3] = __builtin_amdgcn_mfma_f32_32x32x16_bf16(af, bf3, acc[3], 0, 0, 0);
        }
        __syncthreads();
    }

    // ---- fused LSTM epilogue: tile ni == gate ni; col = lane&31,
    //      row = (reg&3) + 8*(reg>>2) + 4*half  (verified m74/m101) ----
    float bias_v[4];
#pragma unroll
    for (int g = 0; g < 4; ++g)
        bias_v[g] = bias_p[bn * 128 + g * 32 + l31];

#pragma unroll
    for (int reg = 0; reg < 16; ++reg) {
        int m_loc = (reg & 3) + 8 * (reg >> 2) + 4 * half;
        size_t m_g = (size_t)(bm * 128 + w * 32 + m_loc);
        float gi = acc[0][reg] + bias_v[0];
        float gf = acc[1][reg] + bias_v[1];
        float gg = acc[2][reg] + bias_v[2];
        float go = acc[3][reg] + bias_v[3];
        float iv = sigmoidf_(gi);
        float fv = sigmoidf_(gf);
        float gv = tanhf_(gg);
        float ov = sigmoidf_(go);
        float cn = fv * c_reg[reg] + iv * gv;
        float hn = ov * tanhf_(cn);
        out[m_g * H_DIM + col]      = hn;   // h_new
        out[BH + m_g * H_DIM + col] = cn;   // c_new
    }
}

// ---------------------------------------------------------------------------
// Fallback path (validated R1 kernels) in case ws_size < 36 MB.
// ---------------------------------------------------------------------------
__global__ __launch_bounds__(256) void prep_weights_fb(
    const float* __restrict__ Wx, const float* __restrict__ Wh,
    const float* __restrict__ bx, const float* __restrict__ bh,
    __hip_bfloat16* __restrict__ Wt, float* __restrict__ bias_p) {
    __shared__ __hip_bfloat16 tile[32][33];
    const int bid = blockIdx.x;
    const int bk  = bid & 31;
    const int bn  = bid >> 5;
    const int t   = threadIdx.x;
    const int kb  = bk * 32, nb = bn * 32;
#pragma unroll
    for (int r = 0; r < 4; ++r) {
        int k_loc = r * 8 + (t >> 5);
        int n_loc = t & 31;
        int kg = kb + k_loc;
        float v = (kg < IN_DIM) ? Wx[(size_t)kg * N4H + nb + n_loc]
                                : Wh[(size_t)(kg - IN_DIM) * N4H + nb + n_loc];
        tile[k_loc][n_loc] = __float2bfloat16(v);
    }
    __syncthreads();
    {
        int n_loc = t >> 3;
        int k_loc = (t & 7) * 4;
        int ng = nb + n_loc;
        int g  = ng >> 9;
        int c  = ng & 511;
        int row_out = (c >> 5) * 128 + g * 32 + (c & 31);
        short4v v4;
        v4.x = *reinterpret_cast<short*>(&tile[k_loc + 0][n_loc]);
        v4.y = *reinterpret_cast<short*>(&tile[k_loc + 1][n_loc]);
        v4.z = *reinterpret_cast<short*>(&tile[k_loc + 2][n_loc]);
        v4.w = *reinterpret_cast<short*>(&tile[k_loc + 3][n_loc]);
        *(short4v*)&Wt[(size_t)row_out * K_DIM + kb + k_loc] = v4;
    }
    if (bid < 8) {
        int ng = bid * 256 + t;
        int g  = ng >> 9;
        int c  = ng & 511;
        int ro = (c >> 5) * 128 + g * 32 + (c & 31);
        bias_p[ro] = bx[ng] + bh[ng];
    }
}

__global__ __launch_bounds__(256, 3) void lstm_gemm_fb(
    const float* __restrict__ x, const float* __restrict__ h,
    const float* __restrict__ c_in,
    const __hip_bfloat16* __restrict__ Wt, const float* __restrict__ bias_p,
    float* __restrict__ out) {
    __shared__ __hip_bfloat16 lds_a[128 * 32];
    __shared__ __hip_bfloat16 lds_b[128 * 32];
    const int tid   = threadIdx.x;
    const int bn    = blockIdx.x & 15;
    const int bm    = blockIdx.x >> 4;
    const int w     = tid >> 6;
    const int lane  = tid & 63;
    const int col16 = lane & 15;
    const int quad  = lane >> 4;
    f32x4 acc[2][8];
#pragma unroll
    for (int mi = 0; mi < 2; ++mi)
#pragma unroll
        for (int ni = 0; ni < 8; ++ni)
            acc[mi][ni] = (f32x4){0.f, 0.f, 0.f, 0.f};
    const __hip_bfloat16* wt_base = Wt + (size_t)(bn * 128) * K_DIM;
    const int chunk0 = w * 2;
    const int e0     = chunk0 * 512 + lane * 8;
    const int bn_loc0 = e0 >> 5, bk_off0 = e0 & 31;
    const int e1     = (chunk0 + 1) * 512 + lane * 8;
    const int bn_loc1 = e1 >> 5, bk_off1 = e1 & 31;
    for (int kt = 0; kt < 32; ++kt) {
        const int kb = kt * 32;
        const float* aptr;
        int koff;
        if (kb < IN_DIM) { aptr = x; koff = kb; }
        else             { aptr = h; koff = kb - IN_DIM; }
        async_load16(wt_base + (size_t)bn_loc0 * K_DIM + kb + bk_off0,
                     (void*)(lds_b + chunk0 * 512));
        async_load16(wt_base + (size_t)bn_loc1 * K_DIM + kb + bk_off1,
                     (void*)(lds_b + (chunk0 + 1) * 512));
        float4 av[4];
#pragma unroll
        for (int j = 0; j < 4; ++j) {
            int cch = j * 256 + tid;
            int row = cch >> 3;
            int kq  = (cch & 7) * 4;
            av[j] = *(const float4*)(aptr + (size_t)(bm * 128 + row) * IN_DIM
                                     + koff + kq);
        }
#pragma unroll
        for (int j = 0; j < 4; ++j) {
            int cch = j * 256 + tid;
            int row = cch >> 3;
            int kq  = (cch & 7) * 4;
            short4v sv;
            sv.x = bf16bits(av[j].x);
            sv.y = bf16bits(av[j].y);
            sv.z = bf16bits(av[j].z);
            sv.w = bf16bits(av[j].w);
            *(short4v*)&lds_a[row * 32 + kq] = sv;
        }
        __syncthreads();
        short8 afr[2], bfr[8];
#pragma unroll
        for (int mi = 0; mi < 2; ++mi)
            afr[mi] = *(const short8*)&lds_a[(w * 32 + mi * 16 + col16) * 32 + quad * 8];
#pragma unroll
        for (int ni = 0; ni < 8; ++ni)
            bfr[ni] = *(const short8*)&lds_b[(ni * 16 + col16) * 32 + quad * 8];
#pragma unroll
        for (int mi = 0; mi < 2; ++mi)
#pragma unroll
            for (int ni = 0; ni < 8; ++ni)
                acc[mi][ni] = __builtin_amdgcn_mfma_f32_16x16x32_bf16(
                    afr[mi], bfr[ni], acc[mi][ni], 0, 0, 0);
        __syncthreads();
    }
    float bias_v[4][2];
#pragma unroll
    for (int g = 0; g < 4; ++g)
#pragma unroll
        for (int h2 = 0; h2 < 2; ++h2)
            bias_v[g][h2] = bias_p[bn * 128 + g * 32 + h2 * 16 + col16];
#pragma unroll
    for (int mi = 0; mi < 2; ++mi) {
#pragma unroll
        for (int reg = 0; reg < 4; ++reg) {
            const int m_g = bm * 128 + w * 32 + mi * 16 + quad * 4 + reg;
#pragma unroll
            for (int h2 = 0; h2 < 2; ++h2) {
                const int hc_g = bn * 32 + h2 * 16 + col16;
                float gi = acc[mi][0 + h2][reg] + bias_v[0][h2];
                float gf = acc[mi][2 + h2][reg] + bias_v[1][h2];
                float gg = acc[mi][4 + h2][reg] + bias_v[2][h2];
                float go = acc[mi][6 + h2][reg] + bias_v[3][h2];
                float iv = sigmoidf_(gi);
                float fv = sigmoidf_(gf);
                float gv = tanhf_(gg);
                float ov = sigmoidf_(go);
                float co = c_in[(size_t)m_g * H_DIM + hc_g];
                float cn = fv * co + iv * gv;
                float hn = ov * tanhf_(cn);
                out[(size_t)m_g * H_DIM + hc_g]      = hn;
                out[BH + (size_t)m_g * H_DIM + hc_g] = cn;
            }
        }
    }
}

extern "C" void kernel_launch(void* const* d_in, const int* in_sizes, int n_in,
                              void* d_out, int out_size, void* d_ws, size_t ws_size,
                              hipStream_t stream) {
    const float* x  = (const float*)d_in[0];
    const float* h  = (const float*)d_in[1];
    const float* c  = (const float*)d_in[2];
    const float* Wx = (const float*)d_in[3];
    const float* Wh = (const float*)d_in[4];
    const float* bx = (const float*)d_in[5];
    const float* bh = (const float*)d_in[6];

    const size_t wtBytes  = (size_t)N4H * K_DIM * 2;    // 4 MB
    const size_t axhBytes = (size_t)B_DIM * K_DIM * 2;  // 32 MB
    const size_t need     = wtBytes + axhBytes + (size_t)N4H * 4;

    if (ws_size >= need) {
        __hip_bfloat16* Wt  = (__hip_bfloat16*)d_ws;
        __hip_bfloat16* Axh = (__hip_bfloat16*)((char*)d_ws + wtBytes);
        float* bias_p = (float*)((char*)d_ws + wtBytes + axhBytes);
        prep_all<<<4096, 256, 0, stream>>>(Wx, Wh, bx, bh, x, h, Wt, Axh, bias_p);
        lstm_gemm<<<2048, 256, 0, stream>>>(c, Axh, Wt, bias_p, (float*)d_out);
    } else {
        __hip_bfloat16* Wt = (__hip_bfloat16*)d_ws;
        float* bias_p = (float*)((char*)d_ws + wtBytes);
        prep_weights_fb<<<2048, 256, 0, stream>>>(Wx, Wh, bx, bh, Wt, bias_p);
        lstm_gemm_fb<<<2048, 256, 0, stream>>>(x, h, c, Wt, bias_p, (float*)d_out);
    }
}

// Round 4
// 249.086 us; speedup vs baseline: 1.1304x; 1.1304x over previous
//
#include <hip/hip_runtime.h>
#include <hip/hip_bf16.h>

// Problem constants (fixed by the reference)
#define B_DIM   16384
#define IN_DIM  512
#define H_DIM   512
#define K_DIM   1024          // IN + H concatenated
#define N4H     2048          // 4*H
#define BH      (B_DIM * H_DIM)

typedef __attribute__((ext_vector_type(8))) short  short8;   // 8 bf16 = one MFMA operand
typedef __attribute__((ext_vector_type(4))) short  short4v;  // 4 bf16 = 8B write
typedef __attribute__((ext_vector_type(4))) float  f32x4;    // MFMA accumulator

__device__ inline void async_load16(const void* g, void* l) {
    __builtin_amdgcn_global_load_lds(
        (const __attribute__((address_space(1))) void*)g,
        (__attribute__((address_space(3)))       void*)l, 16, 0, 0);
}

__device__ inline short bf16bits(float f) {
    __hip_bfloat16 b = __float2bfloat16(f);
    return *reinterpret_cast<short*>(&b);
}

__device__ inline float sigmoidf_(float v) {
    return 1.0f / (1.0f + __expf(-v));
}
__device__ inline float tanhf_(float v) {
    v = fminf(fmaxf(v, -30.f), 30.f);
    float e = __expf(2.f * v);
    return (e - 1.f) / (e + 1.f);
}

// ---------------------------------------------------------------------------
// Combined prep (validated R2):
//   blocks [0,2048):   Wt[row][k] bf16, row permuted nb*128 + gate*32 + col
//   blocks [2048,4096): Axh[m][k] bf16 = x[m]||h[m]
// ---------------------------------------------------------------------------
__global__ __launch_bounds__(256) void prep_all(
    const float* __restrict__ Wx, const float* __restrict__ Wh,
    const float* __restrict__ bx, const float* __restrict__ bh,
    const float* __restrict__ x,  const float* __restrict__ h,
    __hip_bfloat16* __restrict__ Wt, __hip_bfloat16* __restrict__ Axh,
    float* __restrict__ bias_p) {
    const int bid = blockIdx.x;
    const int t   = threadIdx.x;

    if (bid < 2048) {
        __shared__ __hip_bfloat16 tile[32][33];
        const int bk = bid & 31;
        const int bn = bid >> 5;
        const int kb = bk * 32, nb = bn * 32;
#pragma unroll
        for (int r = 0; r < 4; ++r) {
            int k_loc = r * 8 + (t >> 5);
            int n_loc = t & 31;
            int kg = kb + k_loc;
            float v = (kg < IN_DIM) ? Wx[(size_t)kg * N4H + nb + n_loc]
                                    : Wh[(size_t)(kg - IN_DIM) * N4H + nb + n_loc];
            tile[k_loc][n_loc] = __float2bfloat16(v);
        }
        __syncthreads();
        {
            int n_loc = t >> 3;
            int k_loc = (t & 7) * 4;
            int ng = nb + n_loc;
            int g  = ng >> 9;
            int c  = ng & 511;
            int row_out = (c >> 5) * 128 + g * 32 + (c & 31);
            short4v v4;
            v4.x = *reinterpret_cast<short*>(&tile[k_loc + 0][n_loc]);
            v4.y = *reinterpret_cast<short*>(&tile[k_loc + 1][n_loc]);
            v4.z = *reinterpret_cast<short*>(&tile[k_loc + 2][n_loc]);
            v4.w = *reinterpret_cast<short*>(&tile[k_loc + 3][n_loc]);
            *(short4v*)&Wt[(size_t)row_out * K_DIM + kb + k_loc] = v4;
        }
        if (bid < 8) {
            int ng = bid * 256 + t;
            int g  = ng >> 9;
            int c  = ng & 511;
            int ro = (c >> 5) * 128 + g * 32 + (c & 31);
            bias_p[ro] = bx[ng] + bh[ng];
        }
    } else {
        const int ab = bid - 2048;              // 0..2047, 8 rows each
        const int kq = t;                       // float4 index within row
        const float* src = (kq < 128) ? (x + kq * 4)
                                      : (h + (size_t)(kq - 128) * 4);
#pragma unroll
        for (int j = 0; j < 8; ++j) {
            int m = ab * 8 + j;
            float4 v = *(const float4*)(src + (size_t)m * 512);
            short4v sv;
            sv.x = bf16bits(v.x);
            sv.y = bf16bits(v.y);
            sv.z = bf16bits(v.z);
            sv.w = bf16bits(v.w);
            *(short4v*)&Axh[(size_t)m * K_DIM + kq * 4] = sv;
        }
    }
}

// ---------------------------------------------------------------------------
// Main fused kernel: R2's validated structure (128x128 tile, BK=32,
// 16x16x32 MFMA, additive slot swizzle measured conflict-free, XCD pinning)
// + explicit LDS double-buffer: loads for tile kt+1 issued right after the
// barrier publishing tile kt, so the compiler's vmcnt(0)-before-barrier waits
// on loads that have had a full compute phase in flight.
// ---------------------------------------------------------------------------
__global__ __launch_bounds__(256, 3) void lstm_gemm(
    const float* __restrict__ c_in,
    const __hip_bfloat16* __restrict__ Axh,
    const __hip_bfloat16* __restrict__ Wt,
    const float* __restrict__ bias_p,
    float* __restrict__ out) {
    __shared__ __hip_bfloat16 lds_a[2][128 * 32];   // 2 x 8KB
    __shared__ __hip_bfloat16 lds_b[2][128 * 32];   // 2 x 8KB

    const int tid   = threadIdx.x;
    const int w     = tid >> 6;
    const int lane  = tid & 63;
    const int col16 = lane & 15;
    const int quad  = lane >> 4;

    // XCD-aware decomposition (round-robin block->XCD assumed: j & 7)
    const int jb    = blockIdx.x;
    const int xcd   = jb & 7;
    const int local = jb >> 3;                   // 0..255 per XCD
    const int bm    = xcd * 16 + (local >> 4);   // 0..127
    const int bn    = local & 15;                // 0..15

    f32x4 acc[2][8];
#pragma unroll
    for (int mi = 0; mi < 2; ++mi)
#pragma unroll
        for (int ni = 0; ni < 8; ++ni)
            acc[mi][ni] = (f32x4){0.f, 0.f, 0.f, 0.f};

    const __hip_bfloat16* Ab = Axh + (size_t)bm * 128 * K_DIM;
    const __hip_bfloat16* Bb = Wt  + (size_t)bn * 128 * K_DIM;

    // Staging geometry (R2, measured conflict-free):
    // slot s holds row r = s>>2, k-group q = ((s&3) - ((r>>1)&3)) & 3.
    const int s0 = w * 128 + lane;
    const int s1 = s0 + 64;
    const int r0 = s0 >> 2, r1 = s1 >> 2;
    const int q0 = ((s0 & 3) - ((r0 >> 1) & 3)) & 3;
    const int q1 = ((s1 & 3) - ((r1 >> 1) & 3)) & 3;
    const size_t ga0 = (size_t)r0 * K_DIM + q0 * 8;
    const size_t ga1 = (size_t)r1 * K_DIM + q1 * 8;

    // ds_read byte offsets within a buffer (constant across K loop)
    int aoff[2], boff[8];
#pragma unroll
    for (int mi = 0; mi < 2; ++mi) {
        int r = w * 32 + mi * 16 + col16;
        aoff[mi] = (r * 4 + ((quad + ((r >> 1) & 3)) & 3)) * 16;
    }
#pragma unroll
    for (int ni = 0; ni < 8; ++ni) {
        int r = ni * 16 + col16;
        boff[ni] = (r * 4 + ((quad + ((r >> 1) & 3)) & 3)) * 16;
    }

    // Prologue: stage tile kt=0 into buffer 0.
    async_load16(Ab + ga0, (void*)(&lds_a[0][w * 1024]));
    async_load16(Ab + ga1, (void*)(&lds_a[0][w * 1024 + 512]));
    async_load16(Bb + ga0, (void*)(&lds_b[0][w * 1024]));
    async_load16(Bb + ga1, (void*)(&lds_b[0][w * 1024 + 512]));

    for (int kt = 0; kt < 32; ++kt) {
        __syncthreads();                 // drains loads(kt), publishes buf p
        const int p = kt & 1;
        if (kt < 31) {                   // prefetch tile kt+1 into buf 1-p
            const int kb = (kt + 1) * 32;
            async_load16(Ab + ga0 + kb, (void*)(&lds_a[1 - p][w * 1024]));
            async_load16(Ab + ga1 + kb, (void*)(&lds_a[1 - p][w * 1024 + 512]));
            async_load16(Bb + ga0 + kb, (void*)(&lds_b[1 - p][w * 1024]));
            async_load16(Bb + ga1 + kb, (void*)(&lds_b[1 - p][w * 1024 + 512]));
        }
        const char* lap = (const char*)lds_a[p];
        const char* lbp = (const char*)lds_b[p];

        short8 afr[2], bfr[8];
#pragma unroll
        for (int mi = 0; mi < 2; ++mi)
            afr[mi] = *(const short8*)(lap + aoff[mi]);
#pragma unroll
        for (int ni = 0; ni < 8; ++ni)
            bfr[ni] = *(const short8*)(lbp + boff[ni]);
#pragma unroll
        for (int mi = 0; mi < 2; ++mi)
#pragma unroll
            for (int ni = 0; ni < 8; ++ni)
                acc[mi][ni] = __builtin_amdgcn_mfma_f32_16x16x32_bf16(
                    afr[mi], bfr[ni], acc[mi][ni], 0, 0, 0);
    }

    // ---- fused LSTM epilogue (R2, validated) ----
    float bias_v[4][2];
#pragma unroll
    for (int g = 0; g < 4; ++g)
#pragma unroll
        for (int h2 = 0; h2 < 2; ++h2)
            bias_v[g][h2] = bias_p[bn * 128 + g * 32 + h2 * 16 + col16];

#pragma unroll
    for (int mi = 0; mi < 2; ++mi) {
#pragma unroll
        for (int reg = 0; reg < 4; ++reg) {
            const int m_g = bm * 128 + w * 32 + mi * 16 + quad * 4 + reg;
#pragma unroll
            for (int h2 = 0; h2 < 2; ++h2) {
                const int hc_g = bn * 32 + h2 * 16 + col16;
                float gi = acc[mi][0 + h2][reg] + bias_v[0][h2];
                float gf = acc[mi][2 + h2][reg] + bias_v[1][h2];
                float gg = acc[mi][4 + h2][reg] + bias_v[2][h2];
                float go = acc[mi][6 + h2][reg] + bias_v[3][h2];
                float iv = sigmoidf_(gi);
                float fv = sigmoidf_(gf);
                float gv = tanhf_(gg);
                float ov = sigmoidf_(go);
                float co = c_in[(size_t)m_g * H_DIM + hc_g];
                float cn = fv * co + iv * gv;
                float hn = ov * tanhf_(cn);
                out[(size_t)m_g * H_DIM + hc_g]      = hn;   // h_new
                out[BH + (size_t)m_g * H_DIM + hc_g] = cn;   // c_new
            }
        }
    }
}

// ---------------------------------------------------------------------------
// Fallback path (validated R1 kernels) in case ws_size < 36 MB.
// ---------------------------------------------------------------------------
__global__ __launch_bounds__(256) void prep_weights_fb(
    const float* __restrict__ Wx, const float* __restrict__ Wh,
    const float* __restrict__ bx, const float* __restrict__ bh,
    __hip_bfloat16* __restrict__ Wt, float* __restrict__ bias_p) {
    __shared__ __hip_bfloat16 tile[32][33];
    const int bid = blockIdx.x;
    const int bk  = bid & 31;
    const int bn  = bid >> 5;
    const int t   = threadIdx.x;
    const int kb  = bk * 32, nb = bn * 32;
#pragma unroll
    for (int r = 0; r < 4; ++r) {
        int k_loc = r * 8 + (t >> 5);
        int n_loc = t & 31;
        int kg = kb + k_loc;
        float v = (kg < IN_DIM) ? Wx[(size_t)kg * N4H + nb + n_loc]
                                : Wh[(size_t)(kg - IN_DIM) * N4H + nb + n_loc];
        tile[k_loc][n_loc] = __float2bfloat16(v);
    }
    __syncthreads();
    {
        int n_loc = t >> 3;
        int k_loc = (t & 7) * 4;
        int ng = nb + n_loc;
        int g  = ng >> 9;
        int c  = ng & 511;
        int row_out = (c >> 5) * 128 + g * 32 + (c & 31);
        short4v v4;
        v4.x = *reinterpret_cast<short*>(&tile[k_loc + 0][n_loc]);
        v4.y = *reinterpret_cast<short*>(&tile[k_loc + 1][n_loc]);
        v4.z = *reinterpret_cast<short*>(&tile[k_loc + 2][n_loc]);
        v4.w = *reinterpret_cast<short*>(&tile[k_loc + 3][n_loc]);
        *(short4v*)&Wt[(size_t)row_out * K_DIM + kb + k_loc] = v4;
    }
    if (bid < 8) {
        int ng = bid * 256 + t;
        int g  = ng >> 9;
        int c  = ng & 511;
        int ro = (c >> 5) * 128 + g * 32 + (c & 31);
        bias_p[ro] = bx[ng] + bh[ng];
    }
}

__global__ __launch_bounds__(256, 3) void lstm_gemm_fb(
    const float* __restrict__ x, const float* __restrict__ h,
    const float* __restrict__ c_in,
    const __hip_bfloat16* __restrict__ Wt, const float* __restrict__ bias_p,
    float* __restrict__ out) {
    __shared__ __hip_bfloat16 lds_a[128 * 32];
    __shared__ __hip_bfloat16 lds_b[128 * 32];
    const int tid   = threadIdx.x;
    const int bn    = blockIdx.x & 15;
    const int bm    = blockIdx.x >> 4;
    const int w     = tid >> 6;
    const int lane  = tid & 63;
    const int col16 = lane & 15;
    const int quad  = lane >> 4;
    f32x4 acc[2][8];
#pragma unroll
    for (int mi = 0; mi < 2; ++mi)
#pragma unroll
        for (int ni = 0; ni < 8; ++ni)
            acc[mi][ni] = (f32x4){0.f, 0.f, 0.f, 0.f};
    const __hip_bfloat16* wt_base = Wt + (size_t)(bn * 128) * K_DIM;
    const int chunk0 = w * 2;
    const int e0     = chunk0 * 512 + lane * 8;
    const int bn_loc0 = e0 >> 5, bk_off0 = e0 & 31;
    const int e1     = (chunk0 + 1) * 512 + lane * 8;
    const int bn_loc1 = e1 >> 5, bk_off1 = e1 & 31;
    for (int kt = 0; kt < 32; ++kt) {
        const int kb = kt * 32;
        const float* aptr;
        int koff;
        if (kb < IN_DIM) { aptr = x; koff = kb; }
        else             { aptr = h; koff = kb - IN_DIM; }
        async_load16(wt_base + (size_t)bn_loc0 * K_DIM + kb + bk_off0,
                     (void*)(lds_b + chunk0 * 512));
        async_load16(wt_base + (size_t)bn_loc1 * K_DIM + kb + bk_off1,
                     (void*)(lds_b + (chunk0 + 1) * 512));
        float4 av[4];
#pragma unroll
        for (int j = 0; j < 4; ++j) {
            int cch = j * 256 + tid;
            int row = cch >> 3;
            int kq  = (cch & 7) * 4;
            av[j] = *(const float4*)(aptr + (size_t)(bm * 128 + row) * IN_DIM
                                     + koff + kq);
        }
#pragma unroll
        for (int j = 0; j < 4; ++j) {
            int cch = j * 256 + tid;
            int row = cch >> 3;
            int kq  = (cch & 7) * 4;
            short4v sv;
            sv.x = bf16bits(av[j].x);
            sv.y = bf16bits(av[j].y);
            sv.z = bf16bits(av[j].z);
            sv.w = bf16bits(av[j].w);
            *(short4v*)&lds_a[row * 32 + kq] = sv;
        }
        __syncthreads();
        short8 afr[2], bfr[8];
#pragma unroll
        for (int mi = 0; mi < 2; ++mi)
            afr[mi] = *(const short8*)&lds_a[(w * 32 + mi * 16 + col16) * 32 + quad * 8];
#pragma unroll
        for (int ni = 0; ni < 8; ++ni)
            bfr[ni] = *(const short8*)&lds_b[(ni * 16 + col16) * 32 + quad * 8];
#pragma unroll
        for (int mi = 0; mi < 2; ++mi)
#pragma unroll
            for (int ni = 0; ni < 8; ++ni)
                acc[mi][ni] = __builtin_amdgcn_mfma_f32_16x16x32_bf16(
                    afr[mi], bfr[ni], acc[mi][ni], 0, 0, 0);
        __syncthreads();
    }
    float bias_v[4][2];
#pragma unroll
    for (int g = 0; g < 4; ++g)
#pragma unroll
        for (int h2 = 0; h2 < 2; ++h2)
            bias_v[g][h2] = bias_p[bn * 128 + g * 32 + h2 * 16 + col16];
#pragma unroll
    for (int mi = 0; mi < 2; ++mi) {
#pragma unroll
        for (int reg = 0; reg < 4; ++reg) {
            const int m_g = bm * 128 + w * 32 + mi * 16 + quad * 4 + reg;
#pragma unroll
            for (int h2 = 0; h2 < 2; ++h2) {
                const int hc_g = bn * 32 + h2 * 16 + col16;
                float gi = acc[mi][0 + h2][reg] + bias_v[0][h2];
                float gf = acc[mi][2 + h2][reg] + bias_v[1][h2];
                float gg = acc[mi][4 + h2][reg] + bias_v[2][h2];
                float go = acc[mi][6 + h2][reg] + bias_v[3][h2];
                float iv = sigmoidf_(gi);
                float fv = sigmoidf_(gf);
                float gv = tanhf_(gg);
                float ov = sigmoidf_(go);
                float co = c_in[(size_t)m_g * H_DIM + hc_g];
                float cn = fv * co + iv * gv;
                float hn = ov * tanhf_(cn);
                out[(size_t)m_g * H_DIM + hc_g]      = hn;
                out[BH + (size_t)m_g * H_DIM + hc_g] = cn;
            }
        }
    }
}

extern "C" void kernel_launch(void* const* d_in, const int* in_sizes, int n_in,
                              void* d_out, int out_size, void* d_ws, size_t ws_size,
                              hipStream_t stream) {
    const float* x  = (const float*)d_in[0];
    const float* h  = (const float*)d_in[1];
    const float* c  = (const float*)d_in[2];
    const float* Wx = (const float*)d_in[3];
    const float* Wh = (const float*)d_in[4];
    const float* bx = (const float*)d_in[5];
    const float* bh = (const float*)d_in[6];

    const size_t wtBytes  = (size_t)N4H * K_DIM * 2;    // 4 MB
    const size_t axhBytes = (size_t)B_DIM * K_DIM * 2;  // 32 MB
    const size_t need     = wtBytes + axhBytes + (size_t)N4H * 4;

    if (ws_size >= need) {
        __hip_bfloat16* Wt  = (__hip_bfloat16*)d_ws;
        __hip_bfloat16* Axh = (__hip_bfloat16*)((char*)d_ws + wtBytes);
        float* bias_p = (float*)((char*)d_ws + wtBytes + axhBytes);
        prep_all<<<4096, 256, 0, stream>>>(Wx, Wh, bx, bh, x, h, Wt, Axh, bias_p);
        lstm_gemm<<<2048, 256, 0, stream>>>(c, Axh, Wt, bias_p, (float*)d_out);
    } else {
        __hip_bfloat16* Wt = (__hip_bfloat16*)d_ws;
        float* bias_p = (float*)((char*)d_ws + wtBytes);
        prep_weights_fb<<<2048, 256, 0, stream>>>(Wx, Wh, bx, bh, Wt, bias_p);
        lstm_gemm_fb<<<2048, 256, 0, stream>>>(x, h, c, Wt, bias_p, (float*)d_out);
    }
}